// Round 13
// baseline (120.422 us; speedup 1.0000x reference)
//
#include <hip/hip_runtime.h>

// CRF forward logZ. Inputs: words i32 [2048][256], ThetaB f32 [64][128],
// WA f32 [64][64], E f32 [50002][128]. out: f32 [2048].
// ws: Btb FP8-e4m3 [50002][64] = 3.2 MB, row layout [q][kc*4+j] (64 B/row).
//
// R18: revert R17 (hand-written v_cvt_pk_bf16_f32 NaN'd; catalog T12/m240
//      explicitly says don't hand-write cvt_pk). Base = R15 (best, 114.2us).
//      ONE register-only change: per-mt MFMA accumulation split into TWO
//      independent 2-deep chains (kc 0-1 -> D, kc 2-3 -> E2), merged by
//      v_add_f32 at consume. Tests the last unvaried term in the ~610cy
//      step: dependent-MFMA chain latency (4L -> 2L+4). FP sum reorder
//      only; all memory behavior byte-identical to R15.

#define NROWS 50002
#define EOS_T 62
#define BOS_T 63
#define TLEN  256
#define LOG64 4.1588830833596715f

typedef __attribute__((ext_vector_type(4))) short bf16x4;
typedef __attribute__((ext_vector_type(8))) short bf16x8;
typedef __attribute__((ext_vector_type(2))) float f32x2;
typedef __attribute__((ext_vector_type(4))) float f32x4;
typedef __attribute__((ext_vector_type(4))) unsigned int u32x4;

// round-half-up f32->bf16 pair pack (2 add + 1 perm); lo in low 16 bits
static __device__ __forceinline__ unsigned pack_bf2(float lo, float hi) {
    unsigned a = __float_as_uint(lo) + 0x8000u;
    unsigned b = __float_as_uint(hi) + 0x8000u;
    return __builtin_amdgcn_perm(b, a, 0x07060302u);
}
static __device__ __forceinline__ bf16x8 pack8(float4 a, float4 b) {
    union { bf16x8 v; unsigned u[4]; } r;
    r.u[0] = pack_bf2(a.x, a.y); r.u[1] = pack_bf2(a.z, a.w);
    r.u[2] = pack_bf2(b.x, b.y); r.u[3] = pack_bf2(b.z, b.w);
    return r.v;
}
static __device__ __forceinline__ bf16x4 pack4(float f0, float f1, float f2, float f3) {
    union { bf16x4 v; unsigned u[2]; } r;
    r.u[0] = pack_bf2(f0, f1); r.u[1] = pack_bf2(f2, f3);
    return r.v;
}

// one Btb row slice for this lane: 16 contiguous bytes = 1x dwordx4 (crf).
#define GLOAD1(buf, addr)                                                     \
    asm volatile("global_load_dwordx4 %0, %1, off" : "=&v"(buf) : "v"(addr))
#define WLOAD(wd, addr)                                                       \
    asm volatile("global_load_dword %0, %1, off" : "=&v"(wd) : "v"(addr))
#define SWAIT(n)                                                              \
    do { __builtin_amdgcn_sched_barrier(0);                                   \
         asm volatile("s_waitcnt vmcnt(" #n ")");                             \
         __builtin_amdgcn_sched_barrier(0); } while (0)

// one E-row slice for this lane: 4x 32B spans (kc*128 + q-slice), 8x dwordx4.
#define GLOADE(buf, addr)                                                     \
    asm volatile("global_load_dwordx4 %0, %8, off\n\t"                        \
                 "global_load_dwordx4 %1, %8, off offset:16\n\t"              \
                 "global_load_dwordx4 %2, %8, off offset:128\n\t"             \
                 "global_load_dwordx4 %3, %8, off offset:144\n\t"             \
                 "global_load_dwordx4 %4, %8, off offset:256\n\t"             \
                 "global_load_dwordx4 %5, %8, off offset:272\n\t"             \
                 "global_load_dwordx4 %6, %8, off offset:384\n\t"             \
                 "global_load_dwordx4 %7, %8, off offset:400"                 \
                 : "=&v"(buf[0]), "=&v"(buf[1]), "=&v"(buf[2]), "=&v"(buf[3]),\
                   "=&v"(buf[4]), "=&v"(buf[5]), "=&v"(buf[6]), "=&v"(buf[7]) \
                 : "v"(addr))
#define GSTORE1(addr, o)                                                      \
    asm volatile("global_store_dwordx4 %0, %1, off"                           \
                 :: "v"(addr), "v"(o) : "memory")

// ---------------------------------------------------------------------------
// Kernel 1: Btb fp8 row w: byte q*16 + mt*4 + r = e4m3(exp(ThetaB[tag].E[w])),
// tag = mt*16 + q*4 + r; tags 62,63 -> 0. (unchanged from R15)
// ---------------------------------------------------------------------------
__global__ __launch_bounds__(64, 1) void emis_mfma(
    const float* __restrict__ ThetaB, const float* __restrict__ E,
    unsigned* __restrict__ Btb)
{
    const int l = threadIdx.x & 15;
    const int q = threadIdx.x >> 4;

    bf16x8 Af[4][4];
#pragma unroll
    for (int mt = 0; mt < 4; ++mt)
#pragma unroll
        for (int kc = 0; kc < 4; ++kc) {
            const float4* tp = (const float4*)ThetaB + (mt * 16 + l) * 32 + kc * 8 + q * 2;
            Af[mt][kc] = pack8(tp[0], tp[1]);
        }

    const int base0 = blockIdx.x * 64;
    unsigned long long ea[4], sa[4];
#pragma unroll
    for (int it = 0; it < 4; ++it) {
        int row  = base0 + it * 16 + l;
        int rowc = row < NROWS ? row : NROWS - 1;       // clamped rows write
        ea[it] = (unsigned long long)(const char*)E + (unsigned long long)rowc * 512u + (unsigned)(q * 32);
        sa[it] = (unsigned long long)(char*)Btb     + (unsigned long long)rowc * 64u  + (unsigned)(q * 16);
    }

    asm volatile("s_waitcnt vmcnt(0) lgkmcnt(0)");
    __builtin_amdgcn_sched_barrier(0);

    u32x4 b0[8], b1[8], b2[8];
    GLOADE(b0, ea[0]); GLOADE(b1, ea[1]); GLOADE(b2, ea[2]);   // 24 in flight

    auto ctile = [&](u32x4 (&buf)[8], unsigned long long saddr, int refill,
                     unsigned long long raddr) {
        bf16x8 Bf[4];
#pragma unroll
        for (int kc = 0; kc < 4; ++kc)
            Bf[kc] = pack8(*(const float4*)&buf[kc * 2], *(const float4*)&buf[kc * 2 + 1]);
        if (refill) GLOADE(buf, raddr);
        f32x4 D[4];
#pragma unroll
        for (int mt = 0; mt < 4; ++mt) { f32x4 z = {0.f, 0.f, 0.f, 0.f}; D[mt] = z; }
#pragma unroll
        for (int kc = 0; kc < 4; ++kc)
#pragma unroll
            for (int mt = 0; mt < 4; ++mt)
                D[mt] = __builtin_amdgcn_mfma_f32_16x16x32_bf16(Af[mt][kc], Bf[kc], D[mt], 0, 0, 0);
        u32x4 o;
#pragma unroll
        for (int mt = 0; mt < 4; ++mt) {
            float v0 = expf(D[mt][0]), v1 = expf(D[mt][1]);
            float v2 = expf(D[mt][2]), v3 = expf(D[mt][3]);
            if (mt == 3 && q == 3) { v2 = 0.f; v3 = 0.f; }     // tags 62, 63
            int d = __builtin_amdgcn_cvt_pk_fp8_f32(v0, v1, 0, false);
            d     = __builtin_amdgcn_cvt_pk_fp8_f32(v2, v3, d, true);
            o[mt] = (unsigned)d;
        }
        GSTORE1(saddr, o);
    };

    SWAIT(16);                       // T0 ready (L1,L2 remain)
    ctile(b0, sa[0], 1, ea[3]);      // + refill L3, store S0 -> 25 out
    SWAIT(17);                       // retire L1; L2+L3+S0 = 17
    ctile(b1, sa[1], 0, 0);          // store S1 -> 18
    SWAIT(10);                       // retire L2; L3+S0+S1 = 10
    ctile(b2, sa[2], 0, 0);          // store S2 -> 11
    SWAIT(3);                        // retire L3; S0+S1+S2 = 3
    ctile(b0, sa[3], 0, 0);          // T3, store S3
}

// ---------------------------------------------------------------------------
// Kernel 2: fwd/bwd recurrence, fully in registers. Ring depth 14, groups of
// 2 VMEM (1 fp8 gather dwordx4 + 1 word); waits batched: one vmcnt(14) per
// 7 substeps drains 7 groups. fp8 decode via v_cvt_pk_f32_fp8. MFMA
// accumulation split into two independent 2-deep chains (D: kc0-1,
// E2: kc2-3) merged by v_add at consume.
// fwd (wv=0): A = S^T, X' = (S^T X) o e_t; bwd (wv=1): X' = e_t o (S X).
// Join: z = (S^T alpha_127) . (e_128 o q_129) via one LDS tile + dot.
// ---------------------------------------------------------------------------
__global__ __launch_bounds__(128, 1) void crf_fwdbwd(
    const int* __restrict__ words, const float* __restrict__ WA,
    const unsigned* __restrict__ Btb, float* __restrict__ out)
{
    __shared__ float ytile[16 * 68];
    const int lane  = threadIdx.x & 63;
    const int wv    = threadIdx.x >> 6;          // 0 = fwd, 1 = bwd
    const int l     = lane & 15;
    const int q     = lane >> 4;
    const int sbase = blockIdx.x * 16;

    // Transition A-frags. S[i][j] = exp(WA[i][j]) * (j != BOS)/64.
    bf16x4 Sf[4][4];
#pragma unroll
    for (int mt = 0; mt < 4; ++mt)
#pragma unroll
        for (int kc = 0; kc < 4; ++kc) {
            float t[4];
#pragma unroll
            for (int j = 0; j < 4; ++j) {
                const int mg = mt * 16 + l;          // m index
                const int kg = kc * 16 + q * 4 + j;  // k index
                const int ii = wv ? mg : kg;         // WA row
                const int jj = wv ? kg : mg;         // WA col (masked: S's j)
                t[j] = (jj == BOS_T) ? 0.f : expf(WA[ii * 64 + jj]) * 0.015625f;
            }
            Sf[mt][kc] = pack4(t[0], t[1], t[2], t[3]);
        }

    float g[4][4];
#pragma unroll
    for (int kc = 0; kc < 4; ++kc)
#pragma unroll
        for (int e = 0; e < 4; ++e) {
            const int jt = kc * 16 + q * 4 + e;
            g[kc][e] = wv ? expf(WA[jt * 64 + EOS_T]) * 0.015625f
                          : ((jt == BOS_T) ? 0.f : expf(WA[BOS_T * 64 + jt]) * 0.015625f);
        }

    const int wb   = (sbase + l) * TLEN;
    const int tdir = wv ? -1 : 1;
    const int t0   = wv ? 254 : 1;

    // lane's 16B fp8 slice of a Btb row starts at byte q*16
    const unsigned long long btbp   = (unsigned long long)(const char*)Btb + (unsigned)(q * 16);
    const int*               wordsp = words + wb;

    // -------- prologue: 15 words via normal loads, then asm-issue region ----
    const int w0  = wordsp[t0];
    const int w1  = wordsp[t0 + 1  * tdir], w2  = wordsp[t0 + 2  * tdir];
    const int w3  = wordsp[t0 + 3  * tdir], w4  = wordsp[t0 + 4  * tdir];
    const int w5  = wordsp[t0 + 5  * tdir], w6  = wordsp[t0 + 6  * tdir];
    const int w7  = wordsp[t0 + 7  * tdir], w8  = wordsp[t0 + 8  * tdir];
    const int w9  = wordsp[t0 + 9  * tdir], w10 = wordsp[t0 + 10 * tdir];
    const int w11 = wordsp[t0 + 11 * tdir], w12 = wordsp[t0 + 12 * tdir];
    const int w13 = wordsp[t0 + 13 * tdir], w14 = wordsp[t0 + 14 * tdir];

    unsigned long long aI = btbp + (unsigned long long)w0  * 64u;
    unsigned long long a0 = btbp + (unsigned long long)w1  * 64u;
    unsigned long long a1 = btbp + (unsigned long long)w2  * 64u;
    unsigned long long a2 = btbp + (unsigned long long)w3  * 64u;
    unsigned long long a3 = btbp + (unsigned long long)w4  * 64u;
    unsigned long long a4 = btbp + (unsigned long long)w5  * 64u;
    unsigned long long a5 = btbp + (unsigned long long)w6  * 64u;
    unsigned long long a6 = btbp + (unsigned long long)w7  * 64u;
    unsigned long long a7 = btbp + (unsigned long long)w8  * 64u;
    unsigned long long a8 = btbp + (unsigned long long)w9  * 64u;
    unsigned long long a9 = btbp + (unsigned long long)w10 * 64u;
    unsigned long long aA = btbp + (unsigned long long)w11 * 64u;
    unsigned long long aB = btbp + (unsigned long long)w12 * 64u;
    unsigned long long aC = btbp + (unsigned long long)w13 * 64u;
    unsigned long long aD = btbp + (unsigned long long)w14 * 64u;

    // drain ALL compiler-issued vmem so manual vmcnt counts are exact
    asm volatile("s_waitcnt vmcnt(0) lgkmcnt(0)");
    __builtin_amdgcn_sched_barrier(0);

    u32x4 ei, e0, e1, e2, e3, e4, e5, e6, e7, e8, e9, eA, eB, eC, eD;
    int d0, d1, d2, d3, d4, d5, d6, d7, d8, d9, dA, dB, dC, dD;
    // issue groups: [ei:1], then 14x [1 gather + 1 word] = 29 ops
    GLOAD1(ei, aI);
    GLOAD1(e0, a0); WLOAD(d0, (unsigned long long)(wordsp + t0 + 15 * tdir));
    GLOAD1(e1, a1); WLOAD(d1, (unsigned long long)(wordsp + t0 + 16 * tdir));
    GLOAD1(e2, a2); WLOAD(d2, (unsigned long long)(wordsp + t0 + 17 * tdir));
    GLOAD1(e3, a3); WLOAD(d3, (unsigned long long)(wordsp + t0 + 18 * tdir));
    GLOAD1(e4, a4); WLOAD(d4, (unsigned long long)(wordsp + t0 + 19 * tdir));
    GLOAD1(e5, a5); WLOAD(d5, (unsigned long long)(wordsp + t0 + 20 * tdir));
    GLOAD1(e6, a6); WLOAD(d6, (unsigned long long)(wordsp + t0 + 21 * tdir));
    GLOAD1(e7, a7); WLOAD(d7, (unsigned long long)(wordsp + t0 + 22 * tdir));
    GLOAD1(e8, a8); WLOAD(d8, (unsigned long long)(wordsp + t0 + 23 * tdir));
    GLOAD1(e9, a9); WLOAD(d9, (unsigned long long)(wordsp + t0 + 24 * tdir));
    GLOAD1(eA, aA); WLOAD(dA, (unsigned long long)(wordsp + t0 + 25 * tdir));
    GLOAD1(eB, aB); WLOAD(dB, (unsigned long long)(wordsp + t0 + 26 * tdir));
    GLOAD1(eC, aC); WLOAD(dC, (unsigned long long)(wordsp + t0 + 27 * tdir));
    GLOAD1(eD, aD); WLOAD(dD, (unsigned long long)(wordsp + t0 + 28 * tdir));

    SWAIT(28);                                   // ei (oldest 1) complete

    // X init = g o e_{t0}; dword kc = 4 fp8 = tags kc*16+q*4+{0..3}
    bf16x4 X[4];
#pragma unroll
    for (int kc = 0; kc < 4; ++kc) {
        f32x2 p01 = __builtin_amdgcn_cvt_pk_f32_fp8((int)ei[kc], false);
        f32x2 p23 = __builtin_amdgcn_cvt_pk_f32_fp8((int)ei[kc], true);
        X[kc] = pack4(p01[0] * g[kc][0], p01[1] * g[kc][1],
                      p23[0] * g[kc][2], p23[1] * g[kc][3]);
    }

    float xf[4][4];                              // last step's f32 products

    // substep: two independent 2-deep MFMA chains (D: kc0-1, E2: kc2-3);
    // if batch head, ONE vmcnt(14) draining this batch's 7 groups; merge
    // chains + fp8-decode emission; refill for s+14, word for s+28.
    auto substep = [&](u32x4& eb, int& wd, int widx, bool batchwait) {
        f32x4 D[4], E2[4];
#pragma unroll
        for (int mt = 0; mt < 4; ++mt) {
            f32x4 z = {0.f, 0.f, 0.f, 0.f}; D[mt] = z; E2[mt] = z;
        }
#pragma unroll
        for (int mt = 0; mt < 4; ++mt) {
            D[mt]  = __builtin_amdgcn_mfma_f32_16x16x16bf16_1k(Sf[mt][0], X[0], D[mt],  0, 0, 0);
            E2[mt] = __builtin_amdgcn_mfma_f32_16x16x16bf16_1k(Sf[mt][2], X[2], E2[mt], 0, 0, 0);
        }
#pragma unroll
        for (int mt = 0; mt < 4; ++mt) {
            D[mt]  = __builtin_amdgcn_mfma_f32_16x16x16bf16_1k(Sf[mt][1], X[1], D[mt],  0, 0, 0);
            E2[mt] = __builtin_amdgcn_mfma_f32_16x16x16bf16_1k(Sf[mt][3], X[3], E2[mt], 0, 0, 0);
        }
        if (batchwait) SWAIT(14);                // 7 oldest groups (2 ops ea.)
#pragma unroll
        for (int kc = 0; kc < 4; ++kc) {
            f32x2 p01 = __builtin_amdgcn_cvt_pk_f32_fp8((int)eb[kc], false);
            f32x2 p23 = __builtin_amdgcn_cvt_pk_f32_fp8((int)eb[kc], true);
            xf[kc][0] = (D[kc][0] + E2[kc][0]) * p01[0];
            xf[kc][1] = (D[kc][1] + E2[kc][1]) * p01[1];
            xf[kc][2] = (D[kc][2] + E2[kc][2]) * p23[0];
            xf[kc][3] = (D[kc][3] + E2[kc][3]) * p23[1];
            X[kc] = pack4(xf[kc][0], xf[kc][1], xf[kc][2], xf[kc][3]);
        }
        unsigned long long a = btbp + (unsigned long long)wd * 64u;
        GLOAD1(eb, a);
        WLOAD(wd, (unsigned long long)(wordsp + widx));
    };

    // 126 steps = 9 x 14 (two 7-batches per iter); word index bounds:
    // fwd max 1+(112+42)=155<256, bwd min 254-154=100>=0.
    for (int i = 0; i < 126; i += 14) {
        substep(e0, d0, t0 + tdir * (i + 29), true);
        substep(e1, d1, t0 + tdir * (i + 30), false);
        substep(e2, d2, t0 + tdir * (i + 31), false);
        substep(e3, d3, t0 + tdir * (i + 32), false);
        substep(e4, d4, t0 + tdir * (i + 33), false);
        substep(e5, d5, t0 + tdir * (i + 34), false);
        substep(e6, d6, t0 + tdir * (i + 35), false);
        substep(e7, d7, t0 + tdir * (i + 36), true);
        substep(e8, d8, t0 + tdir * (i + 37), false);
        substep(e9, d9, t0 + tdir * (i + 38), false);
        substep(eA, dA, t0 + tdir * (i + 39), false);
        substep(eB, dB, t0 + tdir * (i + 40), false);
        substep(eC, dC, t0 + tdir * (i + 41), false);
        substep(eD, dD, t0 + tdir * (i + 42), false);
    }

    if (wv == 0) {
        // extra step: Y = S^T alpha_127 (no emission) -> LDS
        f32x4 D[4];
#pragma unroll
        for (int mt = 0; mt < 4; ++mt) { f32x4 z = {0.f, 0.f, 0.f, 0.f}; D[mt] = z; }
#pragma unroll
        for (int kc = 0; kc < 4; ++kc)
#pragma unroll
            for (int mt = 0; mt < 4; ++mt)
                D[mt] = __builtin_amdgcn_mfma_f32_16x16x16bf16_1k(Sf[mt][kc], X[kc], D[mt], 0, 0, 0);
#pragma unroll
        for (int mt = 0; mt < 4; ++mt) {
            float4 o = {D[mt][0], D[mt][1], D[mt][2], D[mt][3]};
            *(float4*)&ytile[l * 68 + mt * 16 + q * 4] = o;
        }
    }
    __syncthreads();
    if (wv == 1) {
        // z[s] = sum_tag Y[tag][s] * X128[tag][s]
        float p = 0.f;
#pragma unroll
        for (int mt = 0; mt < 4; ++mt)
#pragma unroll
            for (int r = 0; r < 4; ++r)
                p = fmaf(ytile[l * 68 + mt * 16 + q * 4 + r], xf[mt][r], p);
        p += __shfl_xor(p, 16, 64);
        p += __shfl_xor(p, 32, 64);
        if (lane < 16)
            out[sbase + l] = logf(p) + 255.0f * LOG64;
    }
}

extern "C" void kernel_launch(void* const* d_in, const int* in_sizes, int n_in,
                              void* d_out, int out_size, void* d_ws, size_t ws_size,
                              hipStream_t stream) {
    const int*   words  = (const int*)d_in[0];
    const float* ThetaB = (const float*)d_in[1];
    const float* WA     = (const float*)d_in[2];
    const float* E      = (const float*)d_in[3];
    float*       outp   = (float*)d_out;
    unsigned*    Btb    = (unsigned*)d_ws;       // 50002*64 B = 3.2 MB fp8

    // 782 blocks x 1 wave x 4 word-tiles = 50048 >= 50002 rows
    emis_mfma<<<dim3(782), dim3(64), 0, stream>>>(ThetaB, E, Btb);
    // 128 blocks x (fwd wave + bwd wave), 16 sentences each
    crf_fwdbwd<<<dim3(128), dim3(128), 0, stream>>>(words, WA, Btb, outp);
}

// Round 14
// 114.271 us; speedup vs baseline: 1.0538x; 1.0538x over previous
//
#include <hip/hip_runtime.h>

// CRF forward logZ. Inputs: words i32 [2048][256], ThetaB f32 [64][128],
// WA f32 [64][64], E f32 [50002][128]. out: f32 [2048].
// ws: Btb FP8-e4m3 [50002][64] = 3.2 MB, row layout [q][kc*4+j] (64 B/row).
//
// R19 = exact revert to R15 (best: 114.2us). R18's 2-chain MFMA split
//      regressed 6.2us (extra acc-init + merge VALU dominates; accumulator
//      forwarding was never the bottleneck). Session ledger: crf 58.8->~32us
//      via structural asm ring + 1 gather-VMEM/step + fp8 L2-resident table
//      + batched counted vmcnt. Residual ~610cy/step = serial gather->
//      decode->mul->pack->MFMA chain at L2 latency; invariant to ring depth,
//      wait placement, occupancy, CU spread, chain split (all falsified).
//      ~70us of the 114 is harness-owned (fill + reset dispatches).

#define NROWS 50002
#define EOS_T 62
#define BOS_T 63
#define TLEN  256
#define LOG64 4.1588830833596715f

typedef __attribute__((ext_vector_type(4))) short bf16x4;
typedef __attribute__((ext_vector_type(8))) short bf16x8;
typedef __attribute__((ext_vector_type(2))) float f32x2;
typedef __attribute__((ext_vector_type(4))) float f32x4;
typedef __attribute__((ext_vector_type(4))) unsigned int u32x4;

// round-half-up f32->bf16 pair pack (2 add + 1 perm); lo in low 16 bits
static __device__ __forceinline__ unsigned pack_bf2(float lo, float hi) {
    unsigned a = __float_as_uint(lo) + 0x8000u;
    unsigned b = __float_as_uint(hi) + 0x8000u;
    return __builtin_amdgcn_perm(b, a, 0x07060302u);
}
static __device__ __forceinline__ bf16x8 pack8(float4 a, float4 b) {
    union { bf16x8 v; unsigned u[4]; } r;
    r.u[0] = pack_bf2(a.x, a.y); r.u[1] = pack_bf2(a.z, a.w);
    r.u[2] = pack_bf2(b.x, b.y); r.u[3] = pack_bf2(b.z, b.w);
    return r.v;
}
static __device__ __forceinline__ bf16x4 pack4(float f0, float f1, float f2, float f3) {
    union { bf16x4 v; unsigned u[2]; } r;
    r.u[0] = pack_bf2(f0, f1); r.u[1] = pack_bf2(f2, f3);
    return r.v;
}

// one Btb row slice for this lane: 16 contiguous bytes = 1x dwordx4 (crf).
#define GLOAD1(buf, addr)                                                     \
    asm volatile("global_load_dwordx4 %0, %1, off" : "=&v"(buf) : "v"(addr))
#define WLOAD(wd, addr)                                                       \
    asm volatile("global_load_dword %0, %1, off" : "=&v"(wd) : "v"(addr))
#define SWAIT(n)                                                              \
    do { __builtin_amdgcn_sched_barrier(0);                                   \
         asm volatile("s_waitcnt vmcnt(" #n ")");                             \
         __builtin_amdgcn_sched_barrier(0); } while (0)

// one E-row slice for this lane: 4x 32B spans (kc*128 + q-slice), 8x dwordx4.
#define GLOADE(buf, addr)                                                     \
    asm volatile("global_load_dwordx4 %0, %8, off\n\t"                        \
                 "global_load_dwordx4 %1, %8, off offset:16\n\t"              \
                 "global_load_dwordx4 %2, %8, off offset:128\n\t"             \
                 "global_load_dwordx4 %3, %8, off offset:144\n\t"             \
                 "global_load_dwordx4 %4, %8, off offset:256\n\t"             \
                 "global_load_dwordx4 %5, %8, off offset:272\n\t"             \
                 "global_load_dwordx4 %6, %8, off offset:384\n\t"             \
                 "global_load_dwordx4 %7, %8, off offset:400"                 \
                 : "=&v"(buf[0]), "=&v"(buf[1]), "=&v"(buf[2]), "=&v"(buf[3]),\
                   "=&v"(buf[4]), "=&v"(buf[5]), "=&v"(buf[6]), "=&v"(buf[7]) \
                 : "v"(addr))
#define GSTORE1(addr, o)                                                      \
    asm volatile("global_store_dwordx4 %0, %1, off"                           \
                 :: "v"(addr), "v"(o) : "memory")

// ---------------------------------------------------------------------------
// Kernel 1: Btb fp8 row w: byte q*16 + mt*4 + r = e4m3(exp(ThetaB[tag].E[w])),
// tag = mt*16 + q*4 + r; tags 62,63 -> 0. MFMA GEMM; each lane packs its
// (q, mt) dword via v_cvt_pk_fp8_f32 and stores 16 B contiguous.
// ---------------------------------------------------------------------------
__global__ __launch_bounds__(64, 1) void emis_mfma(
    const float* __restrict__ ThetaB, const float* __restrict__ E,
    unsigned* __restrict__ Btb)
{
    const int l = threadIdx.x & 15;
    const int q = threadIdx.x >> 4;

    bf16x8 Af[4][4];
#pragma unroll
    for (int mt = 0; mt < 4; ++mt)
#pragma unroll
        for (int kc = 0; kc < 4; ++kc) {
            const float4* tp = (const float4*)ThetaB + (mt * 16 + l) * 32 + kc * 8 + q * 2;
            Af[mt][kc] = pack8(tp[0], tp[1]);
        }

    const int base0 = blockIdx.x * 64;
    unsigned long long ea[4], sa[4];
#pragma unroll
    for (int it = 0; it < 4; ++it) {
        int row  = base0 + it * 16 + l;
        int rowc = row < NROWS ? row : NROWS - 1;       // clamped rows write
        ea[it] = (unsigned long long)(const char*)E + (unsigned long long)rowc * 512u + (unsigned)(q * 32);
        sa[it] = (unsigned long long)(char*)Btb     + (unsigned long long)rowc * 64u  + (unsigned)(q * 16);
    }

    asm volatile("s_waitcnt vmcnt(0) lgkmcnt(0)");
    __builtin_amdgcn_sched_barrier(0);

    u32x4 b0[8], b1[8], b2[8];
    GLOADE(b0, ea[0]); GLOADE(b1, ea[1]); GLOADE(b2, ea[2]);   // 24 in flight

    auto ctile = [&](u32x4 (&buf)[8], unsigned long long saddr, int refill,
                     unsigned long long raddr) {
        bf16x8 Bf[4];
#pragma unroll
        for (int kc = 0; kc < 4; ++kc)
            Bf[kc] = pack8(*(const float4*)&buf[kc * 2], *(const float4*)&buf[kc * 2 + 1]);
        if (refill) GLOADE(buf, raddr);
        f32x4 D[4];
#pragma unroll
        for (int mt = 0; mt < 4; ++mt) { f32x4 z = {0.f, 0.f, 0.f, 0.f}; D[mt] = z; }
#pragma unroll
        for (int kc = 0; kc < 4; ++kc)
#pragma unroll
            for (int mt = 0; mt < 4; ++mt)
                D[mt] = __builtin_amdgcn_mfma_f32_16x16x32_bf16(Af[mt][kc], Bf[kc], D[mt], 0, 0, 0);
        u32x4 o;
#pragma unroll
        for (int mt = 0; mt < 4; ++mt) {
            float v0 = expf(D[mt][0]), v1 = expf(D[mt][1]);
            float v2 = expf(D[mt][2]), v3 = expf(D[mt][3]);
            if (mt == 3 && q == 3) { v2 = 0.f; v3 = 0.f; }     // tags 62, 63
            int d = __builtin_amdgcn_cvt_pk_fp8_f32(v0, v1, 0, false);
            d     = __builtin_amdgcn_cvt_pk_fp8_f32(v2, v3, d, true);
            o[mt] = (unsigned)d;
        }
        GSTORE1(saddr, o);
    };

    SWAIT(16);                       // T0 ready (L1,L2 remain)
    ctile(b0, sa[0], 1, ea[3]);      // + refill L3, store S0 -> 25 out
    SWAIT(17);                       // retire L1; L2+L3+S0 = 17
    ctile(b1, sa[1], 0, 0);          // store S1 -> 18
    SWAIT(10);                       // retire L2; L3+S0+S1 = 10
    ctile(b2, sa[2], 0, 0);          // store S2 -> 11
    SWAIT(3);                        // retire L3; S0+S1+S2 = 3
    ctile(b0, sa[3], 0, 0);          // T3, store S3
}

// ---------------------------------------------------------------------------
// Kernel 2: fwd/bwd recurrence, fully in registers. Ring depth 14, groups of
// 2 VMEM (1 fp8 gather dwordx4 + 1 word); waits batched: one vmcnt(14) per
// 7 substeps drains 7 groups. fp8 decode via v_cvt_pk_f32_fp8 (2 per kc).
// fwd (wv=0): A = S^T, X' = (S^T X) o e_t; bwd (wv=1): X' = e_t o (S X).
// Join: z = (S^T alpha_127) . (e_128 o q_129) via one LDS tile + dot.
// ---------------------------------------------------------------------------
__global__ __launch_bounds__(128, 1) void crf_fwdbwd(
    const int* __restrict__ words, const float* __restrict__ WA,
    const unsigned* __restrict__ Btb, float* __restrict__ out)
{
    __shared__ float ytile[16 * 68];
    const int lane  = threadIdx.x & 63;
    const int wv    = threadIdx.x >> 6;          // 0 = fwd, 1 = bwd
    const int l     = lane & 15;
    const int q     = lane >> 4;
    const int sbase = blockIdx.x * 16;

    // Transition A-frags. S[i][j] = exp(WA[i][j]) * (j != BOS)/64.
    bf16x4 Sf[4][4];
#pragma unroll
    for (int mt = 0; mt < 4; ++mt)
#pragma unroll
        for (int kc = 0; kc < 4; ++kc) {
            float t[4];
#pragma unroll
            for (int j = 0; j < 4; ++j) {
                const int mg = mt * 16 + l;          // m index
                const int kg = kc * 16 + q * 4 + j;  // k index
                const int ii = wv ? mg : kg;         // WA row
                const int jj = wv ? kg : mg;         // WA col (masked: S's j)
                t[j] = (jj == BOS_T) ? 0.f : expf(WA[ii * 64 + jj]) * 0.015625f;
            }
            Sf[mt][kc] = pack4(t[0], t[1], t[2], t[3]);
        }

    float g[4][4];
#pragma unroll
    for (int kc = 0; kc < 4; ++kc)
#pragma unroll
        for (int e = 0; e < 4; ++e) {
            const int jt = kc * 16 + q * 4 + e;
            g[kc][e] = wv ? expf(WA[jt * 64 + EOS_T]) * 0.015625f
                          : ((jt == BOS_T) ? 0.f : expf(WA[BOS_T * 64 + jt]) * 0.015625f);
        }

    const int wb   = (sbase + l) * TLEN;
    const int tdir = wv ? -1 : 1;
    const int t0   = wv ? 254 : 1;

    // lane's 16B fp8 slice of a Btb row starts at byte q*16
    const unsigned long long btbp   = (unsigned long long)(const char*)Btb + (unsigned)(q * 16);
    const int*               wordsp = words + wb;

    // -------- prologue: 15 words via normal loads, then asm-issue region ----
    const int w0  = wordsp[t0];
    const int w1  = wordsp[t0 + 1  * tdir], w2  = wordsp[t0 + 2  * tdir];
    const int w3  = wordsp[t0 + 3  * tdir], w4  = wordsp[t0 + 4  * tdir];
    const int w5  = wordsp[t0 + 5  * tdir], w6  = wordsp[t0 + 6  * tdir];
    const int w7  = wordsp[t0 + 7  * tdir], w8  = wordsp[t0 + 8  * tdir];
    const int w9  = wordsp[t0 + 9  * tdir], w10 = wordsp[t0 + 10 * tdir];
    const int w11 = wordsp[t0 + 11 * tdir], w12 = wordsp[t0 + 12 * tdir];
    const int w13 = wordsp[t0 + 13 * tdir], w14 = wordsp[t0 + 14 * tdir];

    unsigned long long aI = btbp + (unsigned long long)w0  * 64u;
    unsigned long long a0 = btbp + (unsigned long long)w1  * 64u;
    unsigned long long a1 = btbp + (unsigned long long)w2  * 64u;
    unsigned long long a2 = btbp + (unsigned long long)w3  * 64u;
    unsigned long long a3 = btbp + (unsigned long long)w4  * 64u;
    unsigned long long a4 = btbp + (unsigned long long)w5  * 64u;
    unsigned long long a5 = btbp + (unsigned long long)w6  * 64u;
    unsigned long long a6 = btbp + (unsigned long long)w7  * 64u;
    unsigned long long a7 = btbp + (unsigned long long)w8  * 64u;
    unsigned long long a8 = btbp + (unsigned long long)w9  * 64u;
    unsigned long long a9 = btbp + (unsigned long long)w10 * 64u;
    unsigned long long aA = btbp + (unsigned long long)w11 * 64u;
    unsigned long long aB = btbp + (unsigned long long)w12 * 64u;
    unsigned long long aC = btbp + (unsigned long long)w13 * 64u;
    unsigned long long aD = btbp + (unsigned long long)w14 * 64u;

    // drain ALL compiler-issued vmem so manual vmcnt counts are exact
    asm volatile("s_waitcnt vmcnt(0) lgkmcnt(0)");
    __builtin_amdgcn_sched_barrier(0);

    u32x4 ei, e0, e1, e2, e3, e4, e5, e6, e7, e8, e9, eA, eB, eC, eD;
    int d0, d1, d2, d3, d4, d5, d6, d7, d8, d9, dA, dB, dC, dD;
    // issue groups: [ei:1], then 14x [1 gather + 1 word] = 29 ops
    GLOAD1(ei, aI);
    GLOAD1(e0, a0); WLOAD(d0, (unsigned long long)(wordsp + t0 + 15 * tdir));
    GLOAD1(e1, a1); WLOAD(d1, (unsigned long long)(wordsp + t0 + 16 * tdir));
    GLOAD1(e2, a2); WLOAD(d2, (unsigned long long)(wordsp + t0 + 17 * tdir));
    GLOAD1(e3, a3); WLOAD(d3, (unsigned long long)(wordsp + t0 + 18 * tdir));
    GLOAD1(e4, a4); WLOAD(d4, (unsigned long long)(wordsp + t0 + 19 * tdir));
    GLOAD1(e5, a5); WLOAD(d5, (unsigned long long)(wordsp + t0 + 20 * tdir));
    GLOAD1(e6, a6); WLOAD(d6, (unsigned long long)(wordsp + t0 + 21 * tdir));
    GLOAD1(e7, a7); WLOAD(d7, (unsigned long long)(wordsp + t0 + 22 * tdir));
    GLOAD1(e8, a8); WLOAD(d8, (unsigned long long)(wordsp + t0 + 23 * tdir));
    GLOAD1(e9, a9); WLOAD(d9, (unsigned long long)(wordsp + t0 + 24 * tdir));
    GLOAD1(eA, aA); WLOAD(dA, (unsigned long long)(wordsp + t0 + 25 * tdir));
    GLOAD1(eB, aB); WLOAD(dB, (unsigned long long)(wordsp + t0 + 26 * tdir));
    GLOAD1(eC, aC); WLOAD(dC, (unsigned long long)(wordsp + t0 + 27 * tdir));
    GLOAD1(eD, aD); WLOAD(dD, (unsigned long long)(wordsp + t0 + 28 * tdir));

    SWAIT(28);                                   // ei (oldest 1) complete

    // X init = g o e_{t0}; dword kc = 4 fp8 = tags kc*16+q*4+{0..3}
    bf16x4 X[4];
#pragma unroll
    for (int kc = 0; kc < 4; ++kc) {
        f32x2 p01 = __builtin_amdgcn_cvt_pk_f32_fp8((int)ei[kc], false);
        f32x2 p23 = __builtin_amdgcn_cvt_pk_f32_fp8((int)ei[kc], true);
        X[kc] = pack4(p01[0] * g[kc][0], p01[1] * g[kc][1],
                      p23[0] * g[kc][2], p23[1] * g[kc][3]);
    }

    float xf[4][4];                              // last step's f32 products

    // substep: MFMA (regs only); if batch head, ONE vmcnt(14) draining this
    // batch's 7 groups; fp8-decode emission, refill for s+14, word for s+28.
    auto substep = [&](u32x4& eb, int& wd, int widx, bool batchwait) {
        f32x4 D[4];
#pragma unroll
        for (int mt = 0; mt < 4; ++mt) { f32x4 z = {0.f, 0.f, 0.f, 0.f}; D[mt] = z; }
#pragma unroll
        for (int kc = 0; kc < 4; ++kc)
#pragma unroll
            for (int mt = 0; mt < 4; ++mt)
                D[mt] = __builtin_amdgcn_mfma_f32_16x16x16bf16_1k(Sf[mt][kc], X[kc], D[mt], 0, 0, 0);
        if (batchwait) SWAIT(14);                // 7 oldest groups (2 ops ea.)
#pragma unroll
        for (int kc = 0; kc < 4; ++kc) {
            f32x2 p01 = __builtin_amdgcn_cvt_pk_f32_fp8((int)eb[kc], false);
            f32x2 p23 = __builtin_amdgcn_cvt_pk_f32_fp8((int)eb[kc], true);
            xf[kc][0] = D[kc][0] * p01[0];  xf[kc][1] = D[kc][1] * p01[1];
            xf[kc][2] = D[kc][2] * p23[0];  xf[kc][3] = D[kc][3] * p23[1];
            X[kc] = pack4(xf[kc][0], xf[kc][1], xf[kc][2], xf[kc][3]);
        }
        unsigned long long a = btbp + (unsigned long long)wd * 64u;
        GLOAD1(eb, a);
        WLOAD(wd, (unsigned long long)(wordsp + widx));
    };

    // 126 steps = 9 x 14 (two 7-batches per iter); word index bounds:
    // fwd max 1+(112+42)=155<256, bwd min 254-154=100>=0.
    for (int i = 0; i < 126; i += 14) {
        substep(e0, d0, t0 + tdir * (i + 29), true);
        substep(e1, d1, t0 + tdir * (i + 30), false);
        substep(e2, d2, t0 + tdir * (i + 31), false);
        substep(e3, d3, t0 + tdir * (i + 32), false);
        substep(e4, d4, t0 + tdir * (i + 33), false);
        substep(e5, d5, t0 + tdir * (i + 34), false);
        substep(e6, d6, t0 + tdir * (i + 35), false);
        substep(e7, d7, t0 + tdir * (i + 36), true);
        substep(e8, d8, t0 + tdir * (i + 37), false);
        substep(e9, d9, t0 + tdir * (i + 38), false);
        substep(eA, dA, t0 + tdir * (i + 39), false);
        substep(eB, dB, t0 + tdir * (i + 40), false);
        substep(eC, dC, t0 + tdir * (i + 41), false);
        substep(eD, dD, t0 + tdir * (i + 42), false);
    }

    if (wv == 0) {
        // extra step: Y = S^T alpha_127 (no emission) -> LDS
        f32x4 D[4];
#pragma unroll
        for (int mt = 0; mt < 4; ++mt) { f32x4 z = {0.f, 0.f, 0.f, 0.f}; D[mt] = z; }
#pragma unroll
        for (int kc = 0; kc < 4; ++kc)
#pragma unroll
            for (int mt = 0; mt < 4; ++mt)
                D[mt] = __builtin_amdgcn_mfma_f32_16x16x16bf16_1k(Sf[mt][kc], X[kc], D[mt], 0, 0, 0);
#pragma unroll
        for (int mt = 0; mt < 4; ++mt) {
            float4 o = {D[mt][0], D[mt][1], D[mt][2], D[mt][3]};
            *(float4*)&ytile[l * 68 + mt * 16 + q * 4] = o;
        }
    }
    __syncthreads();
    if (wv == 1) {
        // z[s] = sum_tag Y[tag][s] * X128[tag][s]
        float p = 0.f;
#pragma unroll
        for (int mt = 0; mt < 4; ++mt)
#pragma unroll
            for (int r = 0; r < 4; ++r)
                p = fmaf(ytile[l * 68 + mt * 16 + q * 4 + r], xf[mt][r], p);
        p += __shfl_xor(p, 16, 64);
        p += __shfl_xor(p, 32, 64);
        if (lane < 16)
            out[sbase + l] = logf(p) + 255.0f * LOG64;
    }
}

extern "C" void kernel_launch(void* const* d_in, const int* in_sizes, int n_in,
                              void* d_out, int out_size, void* d_ws, size_t ws_size,
                              hipStream_t stream) {
    const int*   words  = (const int*)d_in[0];
    const float* ThetaB = (const float*)d_in[1];
    const float* WA     = (const float*)d_in[2];
    const float* E      = (const float*)d_in[3];
    float*       outp   = (float*)d_out;
    unsigned*    Btb    = (unsigned*)d_ws;       // 50002*64 B = 3.2 MB fp8

    // 782 blocks x 1 wave x 4 word-tiles = 50048 >= 50002 rows
    emis_mfma<<<dim3(782), dim3(64), 0, stream>>>(ThetaB, E, Btb);
    // 128 blocks x (fwd wave + bwd wave), 16 sentences each
    crf_fwdbwd<<<dim3(128), dim3(128), 0, stream>>>(words, WA, Btb, outp);
}